// Round 4
// baseline (63.385 us; speedup 1.0000x reference)
//
#include <hip/hip_runtime.h>
#include <math.h>

// Problem constants (from reference)
#define Hc 256      // ScaleSize H
#define Wc 256      // ScaleSize W
#define RHc 512     // resized H
#define RWc 256     // resized W
#define NPK 12      // picks per curve
#define KCUR 32     // curves per batch
#define NCURVE 512  // 16*32
#define NBLK 2048   // write-kernel blocks
#define NCHUNK 65536 // 256MB / 4KB

typedef float f32x4 __attribute__((ext_vector_type(4)));

// out[m, r, w] = 0.01 + 0.9*(w0*(w==idx[h0]) + w1*(w==idx[h1]))
// bilinear 256->512 half-pixel centers along H; W resize identity.
// even r: h1=r/2, h0=h1-1 clamp, (w0,w1)=(0.25,0.75); odd r: h0=r/2, h1=h0+1 clamp, (0.75,0.25)

// ---------------- Kernel 1: per-curve vIdx -> ws (bytes) ----------------
__global__ __launch_bounds__(256) void idx_kernel(const float* __restrict__ vp,
                                                  const float* __restrict__ vmm,
                                                  unsigned char* __restrict__ wsb) {
    __shared__ float xs[NPK];
    __shared__ float fs[NPK];
    __shared__ int   s_nv;

    const int m   = blockIdx.x;        // curve 0..511
    const int tid = threadIdx.x;
    const int b   = m / KCUR;

    const float dtf = (float)(7000.0 / 255.0);

    if (tid == 0) {
        const float vmin = vmm[2 * b + 0];
        const float vmax = vmm[2 * b + 1];
        const float dv   = __fdiv_rn(__fsub_rn(vmax, vmin), 255.0f);
        int nv = 0;
        for (int i = 0; i < NPK; ++i) {
            const float t = vp[(size_t)m * NPK * 2 + i * 2 + 0];
            const float v = vp[(size_t)m * NPK * 2 + i * 2 + 1];
            const bool valid = (t > 0.0f);
            xs[i] = valid ? __fdiv_rn(t, dtf) : INFINITY;
            fs[i] = __fdiv_rn(__fsub_rn(v, vmin), dv);
            nv += valid ? 1 : 0;
        }
        s_nv = nv;
    }
    __syncthreads();

    const int h   = tid;
    const float q = (float)h;
    const int nv  = s_nv;

    int ss = 0;
    #pragma unroll
    for (int i = 0; i < NPK; ++i) ss += (xs[i] <= q) ? 1 : 0;   // searchsorted right

    int himax = nv - 1; if (himax < 1) himax = 1;
    int hi = ss; if (hi < 1) hi = 1; if (hi > himax) hi = himax;
    const int lo = hi - 1;

    const float x0 = xs[lo], x1 = xs[hi];
    const float y0 = fs[lo], y1 = fs[hi];
    const float denom = __fsub_rn(x1, x0);
    const float safe  = (denom > 0.0f) ? denom : 1.0f;
    float val = __fadd_rn(y0,
                    __fmul_rn(__fdiv_rn(__fsub_rn(q, x0), safe),
                              __fsub_rn(y1, y0)));
    int last = nv - 1; if (last < 0) last = 0;
    if (q <= xs[0])    val = fs[0];
    if (q >= xs[last]) val = fs[last];

    float rr = rintf(val);                 // half-to-even == jnp.round
    rr = fminf(fmaxf(rr, 0.0f), 255.0f);
    wsb[m * Hc + h] = (unsigned char)(int)rr;
}

// ---------------- Kernel 2: fill-style grid-stride streaming writes ----------------
// Chunk c (4KB = 4 output rows) at t-th iteration: c = bid + t*NBLK, so the
// instantaneous write frontier is one contiguous 8MB span, like rocclr fill.
__global__ __launch_bounds__(256) void write_kernel(const unsigned char* __restrict__ idx,
                                                    float* __restrict__ out) {
    const int bid  = blockIdx.x;
    const int tid  = threadIdx.x;
    const int wv   = tid >> 6;                 // wave -> row within chunk
    const int lane = tid & 63;
    const int colb = lane * 4;

    #pragma unroll 4
    for (int t = 0; t < NCHUNK / NBLK; ++t) {
        const int c  = bid + t * NBLK;         // global 4KB chunk id
        const int m  = c >> 7;                 // curve
        const int rg = c & 127;                // row-group within curve
        const int r  = rg * 4 + wv;            // output row 0..511

        int h0, h1; float a0, a1;
        if (r & 1) {                           // odd: 0.9*(0.75, 0.25)
            h0 = r >> 1; h1 = h0 + 1; if (h1 > Hc - 1) h1 = Hc - 1;
            a0 = 0.675f; a1 = 0.225f;
        } else {                               // even: 0.9*(0.25, 0.75)
            h1 = r >> 1; h0 = h1 - 1; if (h0 < 0) h0 = 0;
            a0 = 0.225f; a1 = 0.675f;
        }
        const int c0 = idx[m * Hc + h0];       // L2-resident 128KB table
        const int c1 = idx[m * Hc + h1];

        float v0 = 0.01f, v1 = 0.01f, v2 = 0.01f, v3 = 0.01f;
        if (colb + 0 == c0) v0 += a0;  if (colb + 0 == c1) v0 += a1;
        if (colb + 1 == c0) v1 += a0;  if (colb + 1 == c1) v1 += a1;
        if (colb + 2 == c0) v2 += a0;  if (colb + 2 == c1) v2 += a1;
        if (colb + 3 == c0) v3 += a0;  if (colb + 3 == c1) v3 += a1;

        f32x4 val; val.x = v0; val.y = v1; val.z = v2; val.w = v3;
        __builtin_nontemporal_store(val,
            reinterpret_cast<f32x4*>(out + (size_t)c * 1024 + wv * 256 + colb));
    }
}

// ---------------- Fallback: proven single-kernel (R3) ----------------
#define SUBS 4
#define ROWS_PER_SUB (RHc / SUBS)

__global__ __launch_bounds__(256) void cv_kernel(const float* __restrict__ vp,
                                                 const float* __restrict__ vmm,
                                                 float* __restrict__ out) {
    __shared__ float xs[NPK];
    __shared__ float fs[NPK];
    __shared__ int   s_nv;
    __shared__ int   idx[Hc];

    const int bid = blockIdx.x;
    const int m   = bid >> 2;
    const int sub = bid & (SUBS - 1);
    const int tid = threadIdx.x;
    const int b   = m / KCUR;

    const float dtf = (float)(7000.0 / 255.0);

    if (tid == 0) {
        const float vmin = vmm[2 * b + 0];
        const float vmax = vmm[2 * b + 1];
        const float dv   = __fdiv_rn(__fsub_rn(vmax, vmin), 255.0f);
        int nv = 0;
        for (int i = 0; i < NPK; ++i) {
            const float t = vp[(size_t)m * NPK * 2 + i * 2 + 0];
            const float v = vp[(size_t)m * NPK * 2 + i * 2 + 1];
            const bool valid = (t > 0.0f);
            xs[i] = valid ? __fdiv_rn(t, dtf) : INFINITY;
            fs[i] = __fdiv_rn(__fsub_rn(v, vmin), dv);
            nv += valid ? 1 : 0;
        }
        s_nv = nv;
    }
    __syncthreads();

    {
        const int h   = tid;
        const float q = (float)h;
        const int nv  = s_nv;
        int ss = 0;
        #pragma unroll
        for (int i = 0; i < NPK; ++i) ss += (xs[i] <= q) ? 1 : 0;
        int himax = nv - 1; if (himax < 1) himax = 1;
        int hi = ss; if (hi < 1) hi = 1; if (hi > himax) hi = himax;
        const int lo = hi - 1;
        const float x0 = xs[lo], x1 = xs[hi];
        const float y0 = fs[lo], y1 = fs[hi];
        const float denom = __fsub_rn(x1, x0);
        const float safe  = (denom > 0.0f) ? denom : 1.0f;
        float val = __fadd_rn(y0,
                        __fmul_rn(__fdiv_rn(__fsub_rn(q, x0), safe),
                                  __fsub_rn(y1, y0)));
        int last = nv - 1; if (last < 0) last = 0;
        if (q <= xs[0])    val = fs[0];
        if (q >= xs[last]) val = fs[last];
        float rr = rintf(val);
        rr = fminf(fmaxf(rr, 0.0f), 255.0f);
        idx[h] = (int)rr;
    }
    __syncthreads();

    const int lane  = tid & 63;
    const int rsub  = tid >> 6;
    const int colb  = lane * 4;
    const int phase = bid & 31;
    float* outm = out + (size_t)m * RHc * RWc;

    #pragma unroll 4
    for (int it = 0; it < ROWS_PER_SUB / 4; ++it) {
        const int p = (it + phase) & 31;
        const int r = sub * ROWS_PER_SUB + p * 4 + rsub;
        int h0, h1; float w0, w1;
        if (r & 1) { h0 = r >> 1; h1 = h0 + 1; if (h1 > Hc - 1) h1 = Hc - 1; w0 = 0.75f; w1 = 0.25f; }
        else       { h1 = r >> 1; h0 = h1 - 1; if (h0 < 0) h0 = 0;           w0 = 0.25f; w1 = 0.75f; }
        const int c0 = idx[h0];
        const int c1 = idx[h1];
        const float a0 = 0.9f * w0;
        const float a1 = 0.9f * w1;
        float v0 = 0.01f, v1 = 0.01f, v2 = 0.01f, v3 = 0.01f;
        if (colb + 0 == c0) v0 += a0;  if (colb + 0 == c1) v0 += a1;
        if (colb + 1 == c0) v1 += a0;  if (colb + 1 == c1) v1 += a1;
        if (colb + 2 == c0) v2 += a0;  if (colb + 2 == c1) v2 += a1;
        if (colb + 3 == c0) v3 += a0;  if (colb + 3 == c1) v3 += a1;
        f32x4 val; val.x = v0; val.y = v1; val.z = v2; val.w = v3;
        __builtin_nontemporal_store(val,
            reinterpret_cast<f32x4*>(outm + (size_t)r * RWc + colb));
    }
}

extern "C" void kernel_launch(void* const* d_in, const int* in_sizes, int n_in,
                              void* d_out, int out_size, void* d_ws, size_t ws_size,
                              hipStream_t stream) {
    const float* vp  = (const float*)d_in[0];   // VelPoints (16,32,12,2) f32
    const float* vmm = (const float*)d_in[1];   // VMM (16,2) f32
    float* out = (float*)d_out;                 // (16,32,512,256) f32

    if (ws_size >= (size_t)NCURVE * Hc) {
        unsigned char* wsb = (unsigned char*)d_ws;
        idx_kernel<<<dim3(NCURVE), dim3(256), 0, stream>>>(vp, vmm, wsb);
        write_kernel<<<dim3(NBLK), dim3(256), 0, stream>>>(wsb, out);
    } else {
        cv_kernel<<<dim3(NCURVE * SUBS), dim3(256), 0, stream>>>(vp, vmm, out);
    }
}

// Round 5
// 46.221 us; speedup vs baseline: 1.3713x; 1.3713x over previous
//
#include <hip/hip_runtime.h>
#include <math.h>

// Problem constants (from reference)
#define Hc 256      // ScaleSize H
#define Wc 256      // ScaleSize W
#define RHc 512     // resized H
#define RWc 256     // resized W
#define NPK 12      // picks per curve
#define KCUR 32     // curves per batch
#define SUBS 4      // sub-blocks per curve
#define ROWS_PER_SUB (RHc / SUBS)   // 128 output rows per block

typedef float f32x4 __attribute__((ext_vector_type(4)));

// out[m, r, w] = 0.01 + 0.9*(w0*(w==idx[h0]) + w1*(w==idx[h1]))
// bilinear 256->512 half-pixel centers along H; W resize identity.
// even r: h1=r/2, h0=h1-1 clamp, (w0,w1)=(0.25,0.75); odd r: h0=r/2, h1=h0+1 clamp, (0.75,0.25)
//
// R5 experiment: R3 structure (per-block phase rotation over 4KB chunks)
// with PLAIN stores instead of nontemporal — L2 write-buffering smooths the
// HBM writeback like rocclr fill (7 TB/s), while rotation keeps the
// instantaneous address set spread across all channel residues.

__global__ __launch_bounds__(256) void cv_kernel(const float* __restrict__ vp,
                                                 const float* __restrict__ vmm,
                                                 float* __restrict__ out) {
    __shared__ float xs[NPK];
    __shared__ float fs[NPK];
    __shared__ int   s_nv;
    __shared__ int   idx[Hc];

    const int bid = blockIdx.x;
    const int m   = bid >> 2;          // curve 0..511
    const int sub = bid & (SUBS - 1);  // quarter of output rows
    const int tid = threadIdx.x;
    const int b   = m / KCUR;          // batch index

    const float dtf = (float)(7000.0 / 255.0);   // (T1-T0)/(H-1)

    // ---- Phase A: load picks, normalize (sorted prefix is given) ----
    if (tid == 0) {
        const float vmin = vmm[2 * b + 0];
        const float vmax = vmm[2 * b + 1];
        const float dv   = __fdiv_rn(__fsub_rn(vmax, vmin), 255.0f);
        int nv = 0;
        for (int i = 0; i < NPK; ++i) {
            const float t = vp[(size_t)m * NPK * 2 + i * 2 + 0];
            const float v = vp[(size_t)m * NPK * 2 + i * 2 + 1];
            const bool valid = (t > 0.0f);       // tn = t/dt > 0  <=>  t > 0
            xs[i] = valid ? __fdiv_rn(t, dtf) : INFINITY;
            fs[i] = __fdiv_rn(__fsub_rn(v, vmin), dv);
            nv += valid ? 1 : 0;
        }
        s_nv = nv;
    }
    __syncthreads();

    // ---- Phase B: per-h interpolation -> vIdx (np.interp, f32-exact) ----
    {
        const int h   = tid;
        const float q = (float)h;
        const int nv  = s_nv;

        int ss = 0;
        #pragma unroll
        for (int i = 0; i < NPK; ++i) ss += (xs[i] <= q) ? 1 : 0;   // searchsorted right

        int himax = nv - 1; if (himax < 1) himax = 1;
        int hi = ss; if (hi < 1) hi = 1; if (hi > himax) hi = himax;
        const int lo = hi - 1;

        const float x0 = xs[lo], x1 = xs[hi];
        const float y0 = fs[lo], y1 = fs[hi];
        const float denom = __fsub_rn(x1, x0);
        const float safe  = (denom > 0.0f) ? denom : 1.0f;
        float val = __fadd_rn(y0,
                        __fmul_rn(__fdiv_rn(__fsub_rn(q, x0), safe),
                                  __fsub_rn(y1, y0)));
        int last = nv - 1; if (last < 0) last = 0;
        if (q <= xs[0])    val = fs[0];
        if (q >= xs[last]) val = fs[last];

        float rr = rintf(val);                 // half-to-even == jnp.round
        rr = fminf(fmaxf(rr, 0.0f), 255.0f);   // clip to [0, W-1]
        idx[h] = (int)rr;
    }
    __syncthreads();

    // ---- Phase C: stream output rows (float4, PLAIN stores, rotated) ----
    const int lane  = tid & 63;
    const int rsub  = tid >> 6;                    // row within 4KB chunk
    const int colb  = lane * 4;
    const int phase = bid & 31;
    float* outm = out + (size_t)m * RHc * RWc;

    #pragma unroll 4
    for (int it = 0; it < ROWS_PER_SUB / 4; ++it) {
        const int p = (it + phase) & 31;           // bijective chunk permutation
        const int r = sub * ROWS_PER_SUB + p * 4 + rsub;

        int h0, h1; float w0, w1;
        if (r & 1) {                               // odd: c = (r-1)/2 + 0.25
            h0 = r >> 1; h1 = h0 + 1; if (h1 > Hc - 1) h1 = Hc - 1;
            w0 = 0.75f; w1 = 0.25f;
        } else {                                   // even: c = r/2 - 0.25
            h1 = r >> 1; h0 = h1 - 1; if (h0 < 0) h0 = 0;
            w0 = 0.25f; w1 = 0.75f;
        }
        const int c0 = idx[h0];
        const int c1 = idx[h1];
        const float a0 = 0.9f * w0;
        const float a1 = 0.9f * w1;

        float v0 = 0.01f, v1 = 0.01f, v2 = 0.01f, v3 = 0.01f;
        if (colb + 0 == c0) v0 += a0;  if (colb + 0 == c1) v0 += a1;
        if (colb + 1 == c0) v1 += a0;  if (colb + 1 == c1) v1 += a1;
        if (colb + 2 == c0) v2 += a0;  if (colb + 2 == c1) v2 += a1;
        if (colb + 3 == c0) v3 += a0;  if (colb + 3 == c1) v3 += a1;

        f32x4 val; val.x = v0; val.y = v1; val.z = v2; val.w = v3;
        *reinterpret_cast<f32x4*>(outm + (size_t)r * RWc + colb) = val;  // PLAIN store
    }
}

extern "C" void kernel_launch(void* const* d_in, const int* in_sizes, int n_in,
                              void* d_out, int out_size, void* d_ws, size_t ws_size,
                              hipStream_t stream) {
    const float* vp  = (const float*)d_in[0];   // VelPoints (16,32,12,2) f32
    const float* vmm = (const float*)d_in[1];   // VMM (16,2) f32
    float* out = (float*)d_out;                 // (16,32,512,256) f32

    const int nCurves = 16 * 32;                // 512
    cv_kernel<<<dim3(nCurves * SUBS), dim3(256), 0, stream>>>(vp, vmm, out);
}

// Round 6
// 44.724 us; speedup vs baseline: 1.4172x; 1.0335x over previous
//
#include <hip/hip_runtime.h>
#include <math.h>

// Problem constants (from reference)
#define Hc 256      // ScaleSize H
#define Wc 256      // ScaleSize W
#define RHc 512     // resized H
#define RWc 256     // resized W
#define NPK 12      // picks per curve
#define KCUR 32     // curves per batch
#define SUBS 4      // sub-blocks per curve
#define ROWS_PER_SUB (RHc / SUBS)   // 128 output rows per block

typedef float f32x4 __attribute__((ext_vector_type(4)));

// out[m, r, w] = 0.01 + 0.9*(w0*(w==idx[h0]) + w1*(w==idx[h1]))
// bilinear 256->512 half-pixel centers along H; W resize identity.
// even r: h1=r/2, h0=h1-1 clamp, (w0,w1)=(0.25,0.75); odd r: h0=r/2, h1=h0+1 clamp, (0.75,0.25)
//
// R6: R5's winning structure (rotation + PLAIN stores) + micro-opts:
//  - Phase A parallel across 12 lanes (no serial division chain on t0)
//  - parity branch hoisted (r&1 == rsub&1), clamps as min/max
//  - wave-uniform idx reads forced to SGPR via readfirstlane
//  - unroll 8 for deeper store pipelining

__global__ __launch_bounds__(256) void cv_kernel(const float* __restrict__ vp,
                                                 const float* __restrict__ vmm,
                                                 float* __restrict__ out) {
    __shared__ float xs[NPK];
    __shared__ float fs[NPK];
    __shared__ int   s_nv;
    __shared__ int   idx[Hc];

    const int bid = blockIdx.x;
    const int m   = bid >> 2;          // curve 0..511
    const int sub = bid & (SUBS - 1);  // quarter of output rows
    const int tid = threadIdx.x;
    const int b   = m / KCUR;          // batch index

    const float dtf = (float)(7000.0 / 255.0);   // (T1-T0)/(H-1)

    // ---- Phase A: picks -> normalized xp/fp (parallel over 12 lanes) ----
    if (tid < NPK) {
        const float vmin = vmm[2 * b + 0];
        const float vmax = vmm[2 * b + 1];
        const float dv   = __fdiv_rn(__fsub_rn(vmax, vmin), 255.0f);
        const float t = vp[(size_t)m * NPK * 2 + tid * 2 + 0];
        const float v = vp[(size_t)m * NPK * 2 + tid * 2 + 1];
        const bool valid = (t > 0.0f);           // tn = t/dt > 0  <=>  t > 0
        xs[tid] = valid ? __fdiv_rn(t, dtf) : INFINITY;
        fs[tid] = __fdiv_rn(__fsub_rn(v, vmin), dv);
        const unsigned long long mask = __ballot(valid);   // lanes 0..11 only
        if (tid == 0) s_nv = (int)__popcll(mask);
    }
    __syncthreads();

    // ---- Phase B: per-h interpolation -> vIdx (np.interp, f32-exact) ----
    {
        const int h   = tid;
        const float q = (float)h;
        const int nv  = s_nv;

        int ss = 0;
        #pragma unroll
        for (int i = 0; i < NPK; ++i) ss += (xs[i] <= q) ? 1 : 0;   // searchsorted right

        int himax = nv - 1; if (himax < 1) himax = 1;
        int hi = ss; if (hi < 1) hi = 1; if (hi > himax) hi = himax;
        const int lo = hi - 1;

        const float x0 = xs[lo], x1 = xs[hi];
        const float y0 = fs[lo], y1 = fs[hi];
        const float denom = __fsub_rn(x1, x0);
        const float safe  = (denom > 0.0f) ? denom : 1.0f;
        float val = __fadd_rn(y0,
                        __fmul_rn(__fdiv_rn(__fsub_rn(q, x0), safe),
                                  __fsub_rn(y1, y0)));
        int last = nv - 1; if (last < 0) last = 0;
        if (q <= xs[0])    val = fs[0];
        if (q >= xs[last]) val = fs[last];

        float rr = rintf(val);                 // half-to-even == jnp.round
        rr = fminf(fmaxf(rr, 0.0f), 255.0f);   // clip to [0, W-1]
        idx[h] = (int)rr;
    }
    __syncthreads();

    // ---- Phase C: stream output rows (float4 plain stores, rotated) ----
    const int lane  = tid & 63;
    const int rsub  = tid >> 6;                    // row within 4KB chunk
    const int colb  = lane * 4;
    const int phase = bid & 31;
    const int rbase = sub * ROWS_PER_SUB + rsub;   // r = rbase + 4*p
    const bool odd  = (rsub & 1);                  // == r&1 (p*4 is even)
    const float a0  = odd ? 0.675f : 0.225f;       // 0.9 * {0.75,0.25}
    const float a1  = odd ? 0.225f : 0.675f;
    float* outm = out + (size_t)m * RHc * RWc;

    #pragma unroll 8
    for (int it = 0; it < 32; ++it) {
        const int p = (it + phase) & 31;           // bijective chunk permutation
        const int r = rbase + p * 4;
        const int hA = r >> 1;
        const int h0 = odd ? hA : max(hA - 1, 0);
        const int h1 = odd ? min(hA + 1, Hc - 1) : hA;

        const int c0 = __builtin_amdgcn_readfirstlane(idx[h0]);  // wave-uniform
        const int c1 = __builtin_amdgcn_readfirstlane(idx[h1]);

        float v0 = 0.01f, v1 = 0.01f, v2 = 0.01f, v3 = 0.01f;
        if (colb + 0 == c0) v0 += a0;  if (colb + 0 == c1) v0 += a1;
        if (colb + 1 == c0) v1 += a0;  if (colb + 1 == c1) v1 += a1;
        if (colb + 2 == c0) v2 += a0;  if (colb + 2 == c1) v2 += a1;
        if (colb + 3 == c0) v3 += a0;  if (colb + 3 == c1) v3 += a1;

        f32x4 val; val.x = v0; val.y = v1; val.z = v2; val.w = v3;
        *reinterpret_cast<f32x4*>(outm + (size_t)r * RWc + colb) = val;  // PLAIN
    }
}

extern "C" void kernel_launch(void* const* d_in, const int* in_sizes, int n_in,
                              void* d_out, int out_size, void* d_ws, size_t ws_size,
                              hipStream_t stream) {
    const float* vp  = (const float*)d_in[0];   // VelPoints (16,32,12,2) f32
    const float* vmm = (const float*)d_in[1];   // VMM (16,2) f32
    float* out = (float*)d_out;                 // (16,32,512,256) f32

    const int nCurves = 16 * 32;                // 512
    cv_kernel<<<dim3(nCurves * SUBS), dim3(256), 0, stream>>>(vp, vmm, out);
}

// Round 7
// 44.021 us; speedup vs baseline: 1.4399x; 1.0160x over previous
//
#include <hip/hip_runtime.h>
#include <math.h>

// Problem constants (from reference)
#define Hc 256      // ScaleSize H
#define Wc 256      // ScaleSize W
#define RHc 512     // resized H
#define RWc 256     // resized W
#define NPK 12      // picks per curve
#define KCUR 32     // curves per batch

typedef float f32x4 __attribute__((ext_vector_type(4)));

// out[m, r, w] = 0.01 + 0.9*(w0*(w==idx[h0]) + w1*(w==idx[h1]))
// bilinear 256->512 half-pixel centers along H; W resize identity.
// even r: h1=r/2, h0=h1-1 clamp, (w0,w1)=(0.25,0.75); odd r: h0=r/2, h1=h0+1 clamp, (0.75,0.25)
//
// R7 experiment (single variable vs R6): SUBS 4 -> 1. 512 blocks (2/CU), one
// full 512KB curve per block, rotation over 128 chunks. Fewer/longer write
// streams to match fill's low-occupancy regime (fill: 10.6% occ, 7 TB/s).

__global__ __launch_bounds__(256) void cv_kernel(const float* __restrict__ vp,
                                                 const float* __restrict__ vmm,
                                                 float* __restrict__ out) {
    __shared__ float xs[NPK];
    __shared__ float fs[NPK];
    __shared__ int   s_nv;
    __shared__ int   idx[Hc];

    const int bid = blockIdx.x;
    const int m   = bid;               // curve 0..511 (one block per curve)
    const int tid = threadIdx.x;
    const int b   = m / KCUR;          // batch index

    const float dtf = (float)(7000.0 / 255.0);   // (T1-T0)/(H-1)

    // ---- Phase A: picks -> normalized xp/fp (parallel over 12 lanes) ----
    if (tid < NPK) {
        const float vmin = vmm[2 * b + 0];
        const float vmax = vmm[2 * b + 1];
        const float dv   = __fdiv_rn(__fsub_rn(vmax, vmin), 255.0f);
        const float t = vp[(size_t)m * NPK * 2 + tid * 2 + 0];
        const float v = vp[(size_t)m * NPK * 2 + tid * 2 + 1];
        const bool valid = (t > 0.0f);           // tn = t/dt > 0  <=>  t > 0
        xs[tid] = valid ? __fdiv_rn(t, dtf) : INFINITY;
        fs[tid] = __fdiv_rn(__fsub_rn(v, vmin), dv);
        const unsigned long long mask = __ballot(valid);   // lanes 0..11 only
        if (tid == 0) s_nv = (int)__popcll(mask);
    }
    __syncthreads();

    // ---- Phase B: per-h interpolation -> vIdx (np.interp, f32-exact) ----
    {
        const int h   = tid;
        const float q = (float)h;
        const int nv  = s_nv;

        int ss = 0;
        #pragma unroll
        for (int i = 0; i < NPK; ++i) ss += (xs[i] <= q) ? 1 : 0;   // searchsorted right

        int himax = nv - 1; if (himax < 1) himax = 1;
        int hi = ss; if (hi < 1) hi = 1; if (hi > himax) hi = himax;
        const int lo = hi - 1;

        const float x0 = xs[lo], x1 = xs[hi];
        const float y0 = fs[lo], y1 = fs[hi];
        const float denom = __fsub_rn(x1, x0);
        const float safe  = (denom > 0.0f) ? denom : 1.0f;
        float val = __fadd_rn(y0,
                        __fmul_rn(__fdiv_rn(__fsub_rn(q, x0), safe),
                                  __fsub_rn(y1, y0)));
        int last = nv - 1; if (last < 0) last = 0;
        if (q <= xs[0])    val = fs[0];
        if (q >= xs[last]) val = fs[last];

        float rr = rintf(val);                 // half-to-even == jnp.round
        rr = fminf(fmaxf(rr, 0.0f), 255.0f);   // clip to [0, W-1]
        idx[h] = (int)rr;
    }
    __syncthreads();

    // ---- Phase C: stream one full curve (float4 plain stores, rotated) ----
    const int lane  = tid & 63;
    const int rsub  = tid >> 6;                    // row within 4KB chunk
    const int colb  = lane * 4;
    const int phase = bid & 127;
    const bool odd  = (rsub & 1);                  // == r&1 (p*4 is even)
    const float a0  = odd ? 0.675f : 0.225f;       // 0.9 * {0.75,0.25}
    const float a1  = odd ? 0.225f : 0.675f;
    float* outm = out + (size_t)m * RHc * RWc;

    #pragma unroll 8
    for (int it = 0; it < 128; ++it) {
        const int p = (it + phase) & 127;          // bijective chunk permutation
        const int r = p * 4 + rsub;
        const int hA = r >> 1;
        const int h0 = odd ? hA : max(hA - 1, 0);
        const int h1 = odd ? min(hA + 1, Hc - 1) : hA;

        const int c0 = __builtin_amdgcn_readfirstlane(idx[h0]);  // wave-uniform
        const int c1 = __builtin_amdgcn_readfirstlane(idx[h1]);

        float v0 = 0.01f, v1 = 0.01f, v2 = 0.01f, v3 = 0.01f;
        if (colb + 0 == c0) v0 += a0;  if (colb + 0 == c1) v0 += a1;
        if (colb + 1 == c0) v1 += a0;  if (colb + 1 == c1) v1 += a1;
        if (colb + 2 == c0) v2 += a0;  if (colb + 2 == c1) v2 += a1;
        if (colb + 3 == c0) v3 += a0;  if (colb + 3 == c1) v3 += a1;

        f32x4 val; val.x = v0; val.y = v1; val.z = v2; val.w = v3;
        *reinterpret_cast<f32x4*>(outm + (size_t)r * RWc + colb) = val;  // PLAIN
    }
}

extern "C" void kernel_launch(void* const* d_in, const int* in_sizes, int n_in,
                              void* d_out, int out_size, void* d_ws, size_t ws_size,
                              hipStream_t stream) {
    const float* vp  = (const float*)d_in[0];   // VelPoints (16,32,12,2) f32
    const float* vmm = (const float*)d_in[1];   // VMM (16,2) f32
    float* out = (float*)d_out;                 // (16,32,512,256) f32

    const int nCurves = 16 * 32;                // 512
    cv_kernel<<<dim3(nCurves), dim3(256), 0, stream>>>(vp, vmm, out);
}